// Round 15
// baseline (1159.870 us; speedup 1.0000x reference)
//
#include <hip/hip_runtime.h>
#include <hip/hip_fp16.h>
#include <hip/hip_cooperative_groups.h>

#define NB 4
#define NN 20000
#define NE 320000
#define ND 64
#define NR 64
#define NT 1000
#define NL 6
#define LN_EPS 1e-5f
#define CAP 64    // deg ~ Poisson(16), P(deg>64) ~ 5e-19
#define GRID 1024 // 4 blocks/CU x 256 CUs, conservative co-residency

typedef _Float16 half8 __attribute__((ext_vector_type(8)));
typedef _Float16 half4v __attribute__((ext_vector_type(4)));
typedef float floatx4 __attribute__((ext_vector_type(4)));

// r15 = r13 bodies + cooperative mega-kernel with GRID=1024 /
// __launch_bounds__(256,4) and a RETURN-CODE-CHECKED launch with fallback
// to the r13 per-layer path (r14's coop launch failed validation silently).

// ---------------------------------------------------------------- prep 1
__global__ void __launch_bounds__(256)
prep1(int* __restrict__ cnt,
      const float* __restrict__ cw, _Float16* __restrict__ cwt,
      const float* __restrict__ relrep, const int* __restrict__ r_index,
      float* __restrict__ query,
      const float* __restrict__ rp_w1, const float* __restrict__ rp_b1,
      const float* __restrict__ rp_w2, const float* __restrict__ rp_b2,
      __half* __restrict__ rel16) {
    int blk = blockIdx.x, tid = threadIdx.x;
    if (blk < 79) {
        int i = blk * 256 + tid;
        if (i < NN) cnt[i] = 0;
    } else if (blk < 271) {
        int i = (blk - 79) * 256 + tid;             // NL*128*64 = 192*256
        int l = i >> 13, rem = i & 8191, k = rem >> 6, n = rem & 63;
        cwt[l * 8192 + n * 128 + k] = (_Float16)cw[i];
    } else if (blk == 271) {
        int b = tid >> 6, d = tid & 63;
        query[tid] = relrep[(b * NR + r_index[b]) * ND + d];
    } else {
        int u = blk - 272;                          // 0..383 = l*NR + r
        int l = u >> 6, r = u & 63;
        int b = tid >> 6, j = tid & 63;
        const float* w1 = rp_w1 + l * ND * ND;
        const float* w2 = rp_w2 + l * ND * ND;
        float xin = relrep[(b * NR + r) * ND + j];
        float acc = rp_b1[l * ND + j];
        #pragma unroll 8
        for (int k = 0; k < ND; ++k) acc += __shfl(xin, k) * w1[k * ND + j];
        float hmid = fmaxf(acc, 0.f);
        float outv = rp_b2[l * ND + j];
        #pragma unroll 8
        for (int k = 0; k < ND; ++k) outv += __shfl(hmid, k) * w2[k * ND + j];
        rel16[l * (NR * NB * ND) + (r * NB + b) * ND + j] = __float2half(outv);
    }
}

// ---------------------------------------------------------------- prep 2
__global__ void __launch_bounds__(256)
prep2(const int* __restrict__ ei, const int* __restrict__ et,
      const float* __restrict__ ew, int* __restrict__ cnt,
      int4* __restrict__ epack) {
    int e = blockIdx.x * 256 + threadIdx.x;         // NE = 1250*256 exactly
    int d = ei[NE + e];
    int p = atomicAdd(&cnt[d], 1);
    if (p < CAP)
        epack[d * CAP + p] = make_int4(ei[e], et[e], __float_as_int(ew[e]), 0);
}

__device__ __forceinline__ float2 h2f(unsigned u) {
    __half2 h = *(__half2*)&u;
    return __half22float2(h);
}
__device__ __forceinline__ __half2 u2h2(unsigned u) { return *(__half2*)&u; }

// --------------------------------------------- shared epilogue (MFMA+LN)
__device__ __forceinline__ void conv_ln_epilogue(
        _Float16* A16, float* sD, int wv, int lane, int n,
        const _Float16* __restrict__ cwt, const float* __restrict__ cb,
        const float* __restrict__ g, const float* __restrict__ bb,
        __half* __restrict__ xo16) {
    __syncthreads();
    {
        int m = lane & 15, quad = lane >> 4;
        int ncol = wv * 16 + m;
        floatx4 acc = {0.f, 0.f, 0.f, 0.f};
        #pragma unroll
        for (int k0 = 0; k0 < 128; k0 += 32) {
            half8 a = *(const half8*)&A16[m * 136 + k0 + quad * 8];
            half8 bfr = *(const half8*)&cwt[ncol * 128 + k0 + quad * 8];
            acc = __builtin_amdgcn_mfma_f32_16x16x32_f16(a, bfr, acc, 0, 0, 0);
        }
        #pragma unroll
        for (int rg = 0; rg < 4; ++rg)
            sD[(quad * 4 + rg) * 65 + ncol] = acc[rg];
    }
    __syncthreads();
    float gl = g[lane], bl = bb[lane], cbl = cb[lane];
    #pragma unroll
    for (int b = 0; b < NB; ++b) {
        float acc = sD[(wv * 4 + b) * 65 + lane] + cbl;
        float s = acc, s2 = acc * acc;
        #pragma unroll
        for (int o = 32; o > 0; o >>= 1) { s += __shfl_xor(s, o); s2 += __shfl_xor(s2, o); }
        float mu  = s * (1.f / ND);
        float var = s2 * (1.f / ND) - mu * mu;
        float hn  = (acc - mu) * rsqrtf(var + LN_EPS) * gl + bl;
        float xvf = (float)A16[(wv * 4 + b) * 136 + lane];
        float v   = fmaxf(hn, 0.f) + xvf;
        xo16[(n * NB + b) * ND + lane] = __float2half(v);
    }
}

// ------------------------------------------------ layer 1 unit (x0 sparse)
__device__ __forceinline__ void first_unit(
        int n, int wv, int lane,
        const __half* __restrict__ rel16, const int* __restrict__ cnt,
        const int4* __restrict__ epack, const float* __restrict__ query,
        const int* __restrict__ h_index, const _Float16* __restrict__ cwt,
        const float* __restrict__ cb, const float* __restrict__ g,
        const float* __restrict__ bb, __half* __restrict__ xo16,
        _Float16* A16, float* sD) {
    int cn = min(cnt[n], CAP);
    int bidx = lane >> 4, c4 = (lane & 15) << 2;
    int hb = h_index[bidx];

    const uint2* __restrict__ r2 = (const uint2*)rel16;
    float4 q4 = ((const float4*)query)[lane];
    half4v qh;
    qh.x = (_Float16)q4.x; qh.y = (_Float16)q4.y;
    qh.z = (_Float16)q4.z; qh.w = (_Float16)q4.w;
    float qx = (float)qh.x, qy = (float)qh.y, qz = (float)qh.z, qw = (float)qh.w;

    float4 agg4 = make_float4(0.f, 0.f, 0.f, 0.f);
    {
        int4 ed = make_int4(0, 0, 0, 0);
        if (lane < cn) ed = epack[n * CAP + lane];
        for (int j = 0; j < cn; ++j) {
            int s   = __shfl(ed.x, j);
            int t   = __shfl(ed.y, j);
            float w = __int_as_float(__shfl(ed.z, j));
            if (s == hb) {
                uint2 ra = r2[t * 64 + lane];
                float2 q0 = h2f(ra.x), q1 = h2f(ra.y);
                agg4.x = fmaf(qx * q0.x, w, agg4.x);
                agg4.y = fmaf(qy * q0.y, w, agg4.y);
                agg4.z = fmaf(qz * q1.x, w, agg4.z);
                agg4.w = fmaf(qw * q1.y, w, agg4.w);
            }
        }
    }
    if (n == hb) {
        agg4.x += q4.x; agg4.y += q4.y; agg4.z += q4.z; agg4.w += q4.w;
    }
    {
        int r = wv * 4 + bidx;
        half4v xh = {0, 0, 0, 0};
        if (n == hb) xh = qh;
        *(half4v*)&A16[r * 136 + c4] = xh;
        half4v ah;
        ah.x = (_Float16)agg4.x; ah.y = (_Float16)agg4.y;
        ah.z = (_Float16)agg4.z; ah.w = (_Float16)agg4.w;
        *(half4v*)&A16[r * 136 + 64 + c4] = ah;
    }
    conv_ln_epilogue(A16, sD, wv, lane, n, cwt, cb, g, bb, xo16);
}

// ------------------------------------------------ generic layer unit
__device__ __forceinline__ void layer_unit(
        int n, int wv, int lane,
        const __half* __restrict__ x16, const __half* __restrict__ rel16,
        const int* __restrict__ cnt, const int4* __restrict__ epack,
        const float* __restrict__ query, const int* __restrict__ h_index,
        const _Float16* __restrict__ cwt, const float* __restrict__ cb,
        const float* __restrict__ g, const float* __restrict__ bb,
        __half* __restrict__ xo16, _Float16* A16, float* sD) {
    int cn = min(cnt[n], CAP);
    int hf = lane >> 5, sub = lane & 31;

    const uint4* __restrict__ x4 = (const uint4*)x16;   // 16 B = 8 halves
    const uint4* __restrict__ r4 = (const uint4*)rel16;

    float acc[8] = {0.f, 0.f, 0.f, 0.f, 0.f, 0.f, 0.f, 0.f};
    {
        int4 ed = make_int4(0, 0, 0, 0);
        if (lane < cn) ed = epack[n * CAP + lane];
        int j = 0;
        for (; j + 4 <= cn; j += 4) {
            int ja = j + hf, jb = j + 2 + hf;
            int sa = __shfl(ed.x, ja), ta = __shfl(ed.y, ja);
            int sb = __shfl(ed.x, jb), tb = __shfl(ed.y, jb);
            float wa = __int_as_float(__shfl(ed.z, ja));
            float wb = __int_as_float(__shfl(ed.z, jb));
            uint4 xa = x4[sa * 32 + sub], ra = r4[ta * 32 + sub];
            uint4 xb = x4[sb * 32 + sub], rb = r4[tb * 32 + sub];
            __half2 p0, p1, p2, p3;
            p0 = __hmul2(u2h2(xa.x), u2h2(ra.x));
            p1 = __hmul2(u2h2(xa.y), u2h2(ra.y));
            p2 = __hmul2(u2h2(xa.z), u2h2(ra.z));
            p3 = __hmul2(u2h2(xa.w), u2h2(ra.w));
            acc[0] = fmaf(__low2float(p0),  wa, acc[0]);
            acc[1] = fmaf(__high2float(p0), wa, acc[1]);
            acc[2] = fmaf(__low2float(p1),  wa, acc[2]);
            acc[3] = fmaf(__high2float(p1), wa, acc[3]);
            acc[4] = fmaf(__low2float(p2),  wa, acc[4]);
            acc[5] = fmaf(__high2float(p2), wa, acc[5]);
            acc[6] = fmaf(__low2float(p3),  wa, acc[6]);
            acc[7] = fmaf(__high2float(p3), wa, acc[7]);
            p0 = __hmul2(u2h2(xb.x), u2h2(rb.x));
            p1 = __hmul2(u2h2(xb.y), u2h2(rb.y));
            p2 = __hmul2(u2h2(xb.z), u2h2(rb.z));
            p3 = __hmul2(u2h2(xb.w), u2h2(rb.w));
            acc[0] = fmaf(__low2float(p0),  wb, acc[0]);
            acc[1] = fmaf(__high2float(p0), wb, acc[1]);
            acc[2] = fmaf(__low2float(p1),  wb, acc[2]);
            acc[3] = fmaf(__high2float(p1), wb, acc[3]);
            acc[4] = fmaf(__low2float(p2),  wb, acc[4]);
            acc[5] = fmaf(__high2float(p2), wb, acc[5]);
            acc[6] = fmaf(__low2float(p3),  wb, acc[6]);
            acc[7] = fmaf(__high2float(p3), wb, acc[7]);
        }
        for (; j < cn; j += 2) {
            int ja = j + hf;                 // zero-padded lanes add exact 0
            int sa = __shfl(ed.x, ja), ta = __shfl(ed.y, ja);
            float wa = __int_as_float(__shfl(ed.z, ja));
            uint4 xa = x4[sa * 32 + sub], ra = r4[ta * 32 + sub];
            __half2 p0 = __hmul2(u2h2(xa.x), u2h2(ra.x));
            __half2 p1 = __hmul2(u2h2(xa.y), u2h2(ra.y));
            __half2 p2 = __hmul2(u2h2(xa.z), u2h2(ra.z));
            __half2 p3 = __hmul2(u2h2(xa.w), u2h2(ra.w));
            acc[0] = fmaf(__low2float(p0),  wa, acc[0]);
            acc[1] = fmaf(__high2float(p0), wa, acc[1]);
            acc[2] = fmaf(__low2float(p1),  wa, acc[2]);
            acc[3] = fmaf(__high2float(p1), wa, acc[3]);
            acc[4] = fmaf(__low2float(p2),  wa, acc[4]);
            acc[5] = fmaf(__high2float(p2), wa, acc[5]);
            acc[6] = fmaf(__low2float(p3),  wa, acc[6]);
            acc[7] = fmaf(__high2float(p3), wa, acc[7]);
        }
    }
    #pragma unroll
    for (int k = 0; k < 8; ++k) acc[k] += __shfl_xor(acc[k], 32);
    int bq = sub >> 3, ch = (sub & 7) << 3;
    if (hf == 0) {
        if (n == h_index[bq]) {
            const float* qp = query + bq * 64 + ch;
            #pragma unroll
            for (int k = 0; k < 8; ++k) acc[k] += qp[k];
        }
        int r = wv * 4 + bq;
        half8 ah;
        #pragma unroll
        for (int k = 0; k < 8; ++k) ah[k] = (_Float16)acc[k];
        *(half8*)&A16[r * 136 + 64 + ch] = ah;
    }
    {
        int bidx = lane >> 4, c4 = (lane & 15) << 2;
        int r = wv * 4 + bidx;
        const uint2* __restrict__ x2 = (const uint2*)x16;
        uint2 xraw = x2[(n * NB + bidx) * 16 + (lane & 15)];
        *(uint2*)&A16[r * 136 + c4] = xraw;
    }
    conv_ln_epilogue(A16, sD, wv, lane, n, cwt, cb, g, bb, xo16);
}

// ------------------------------------------------ scorer unit
__device__ __forceinline__ void score_unit(
        int gid, int lane, const __half* __restrict__ x16,
        const float* __restrict__ query, const int* __restrict__ t_index,
        const float* __restrict__ w1, const float* __restrict__ b1,
        const float* __restrict__ w2, const float* __restrict__ b2,
        float* __restrict__ out) {
    int b = gid / NT;
    int ti = t_index[gid];
    float xv = __half2float(x16[(ti * NB + b) * ND + lane]);
    float qv = query[b * ND + lane];
    float a0 = b1[lane], a1 = b1[lane + 64];
    #pragma unroll 8
    for (int k = 0; k < ND; ++k) {
        float f = __shfl(xv, k);
        a0 += f * w1[k * 128 + lane];
        a1 += f * w1[k * 128 + lane + 64];
    }
    #pragma unroll 8
    for (int k = 0; k < ND; ++k) {
        float f = __shfl(qv, k);
        a0 += f * w1[(ND + k) * 128 + lane];
        a1 += f * w1[(ND + k) * 128 + lane + 64];
    }
    a0 = fmaxf(a0, 0.f);
    a1 = fmaxf(a1, 0.f);
    float p = a0 * w2[lane] + a1 * w2[lane + 64];
    #pragma unroll
    for (int o = 32; o > 0; o >>= 1) p += __shfl_xor(p, o);
    if (lane == 0) out[gid] = p + b2[0];
}

// ------------------------------------------------ standalone kernels (fallback)
__global__ void __launch_bounds__(256)
fused_layer_first_k(const __half* __restrict__ rel16,
                    const int* __restrict__ cnt, const int4* __restrict__ epack,
                    const float* __restrict__ query, const int* __restrict__ h_index,
                    const _Float16* __restrict__ cwt, const float* __restrict__ cb,
                    const float* __restrict__ g, const float* __restrict__ bb,
                    __half* __restrict__ xo16) {
    __shared__ _Float16 A16[16 * 136];
    __shared__ float sD[16 * 65];
    int wv = threadIdx.x >> 6, lane = threadIdx.x & 63;
    first_unit(blockIdx.x * 4 + wv, wv, lane, rel16, cnt, epack, query,
               h_index, cwt, cb, g, bb, xo16, A16, sD);
}

__global__ void __launch_bounds__(256)
fused_layer_k(const __half* __restrict__ x16, const __half* __restrict__ rel16,
              const int* __restrict__ cnt, const int4* __restrict__ epack,
              const float* __restrict__ query, const int* __restrict__ h_index,
              const _Float16* __restrict__ cwt, const float* __restrict__ cb,
              const float* __restrict__ g, const float* __restrict__ bb,
              __half* __restrict__ xo16) {
    __shared__ _Float16 A16[16 * 136];
    __shared__ float sD[16 * 65];
    int wv = threadIdx.x >> 6, lane = threadIdx.x & 63;
    layer_unit(blockIdx.x * 4 + wv, wv, lane, x16, rel16, cnt, epack, query,
               h_index, cwt, cb, g, bb, xo16, A16, sD);
}

__global__ void __launch_bounds__(256)
final_score_k(const __half* __restrict__ x16, const float* __restrict__ query,
              const int* __restrict__ t_index,
              const float* __restrict__ w1, const float* __restrict__ b1,
              const float* __restrict__ w2, const float* __restrict__ b2,
              float* __restrict__ out) {
    int wv = threadIdx.x >> 6, lane = threadIdx.x & 63;
    score_unit(blockIdx.x * 4 + wv, lane, x16, query, t_index, w1, b1, w2, b2, out);
}

// ------------------------------------------------ persistent mega kernel
__global__ void __launch_bounds__(256, 4)
mega(__half* xa, __half* xb, const int* cnt, const int4* epack,
     const __half* rel16, const float* query, const int* h_index,
     const _Float16* cwt, const float* conv_b, const float* ln_g,
     const float* ln_b, const int* t_index, const float* mw1,
     const float* mb1, const float* mw2, const float* mb2, float* out) {
    cooperative_groups::grid_group grid = cooperative_groups::this_grid();
    __shared__ _Float16 A16[16 * 136];
    __shared__ float sD[16 * 65];
    int wv = threadIdx.x >> 6;
    int lane = threadIdx.x & 63;

    for (int u = blockIdx.x; u < NN / 4; u += GRID) {
        __syncthreads();    // A16/sD reuse guard across units
        first_unit(u * 4 + wv, wv, lane, rel16, cnt, epack, query, h_index,
                   cwt, conv_b, ln_g, ln_b, xa, A16, sD);
    }
    grid.sync();
    __half* cur = xa;
    __half* nxt = xb;
    for (int l = 1; l < NL; ++l) {
        const __half*    r_l  = rel16 + l * (NR * NB * ND);
        const _Float16*  w_l  = cwt + l * 8192;
        const float*     cb_l = conv_b + l * ND;
        const float*     g_l  = ln_g + l * ND;
        const float*     b_l  = ln_b + l * ND;
        for (int u = blockIdx.x; u < NN / 4; u += GRID) {
            __syncthreads();
            layer_unit(u * 4 + wv, wv, lane, cur, r_l, cnt, epack, query,
                       h_index, w_l, cb_l, g_l, b_l, nxt, A16, sD);
        }
        grid.sync();
        __half* t = cur; cur = nxt; nxt = t;
    }
    for (int u = blockIdx.x; u < (NB * NT) / 4; u += GRID) {
        score_unit(u * 4 + wv, lane, cur, query, t_index,
                   mw1, mb1, mw2, mb2, out);
    }
}

extern "C" void kernel_launch(void* const* d_in, const int* in_sizes, int n_in,
                              void* d_out, int out_size, void* d_ws, size_t ws_size,
                              hipStream_t stream) {
    const int*   edge_index  = (const int*)d_in[0];
    const int*   edge_type   = (const int*)d_in[1];
    const float* relrep      = (const float*)d_in[2];
    const int*   h_index     = (const int*)d_in[3];
    const int*   r_index     = (const int*)d_in[4];
    const int*   t_index     = (const int*)d_in[5];
    const float* edge_weight = (const float*)d_in[6];
    const float* rp_w1  = (const float*)d_in[7];
    const float* rp_b1  = (const float*)d_in[8];
    const float* rp_w2  = (const float*)d_in[9];
    const float* rp_b2  = (const float*)d_in[10];
    const float* conv_w = (const float*)d_in[11];
    const float* conv_b = (const float*)d_in[12];
    const float* ln_g   = (const float*)d_in[13];
    const float* ln_b   = (const float*)d_in[14];
    const float* mlp_w1 = (const float*)d_in[15];
    const float* mlp_b1 = (const float*)d_in[16];
    const float* mlp_w2 = (const float*)d_in[17];
    const float* mlp_b2 = (const float*)d_in[18];
    float* out = (float*)d_out;

    const int BND = NB * NN * ND;              // 5,120,000
    const int RELSZ = NR * NB * ND;            // 16384
    float*    ws     = (float*)d_ws;
    float*    query  = ws;                         // 256 f
    __half*   rel16  = (__half*)(query + 256);     // NL*RELSZ halves
    __half*   x16a   = rel16 + NL * RELSZ;
    __half*   x16b   = x16a + BND;
    _Float16* cwt16  = (_Float16*)(x16b + BND);    // NL*8192 halves
    int4*     epack  = (int4*)(cwt16 + NL * 8192); // NN*CAP int4 (20.5 MB)
    int*      cnt    = (int*)(epack + NN * CAP);   // NN

    prep1<<<656, 256, 0, stream>>>(cnt, conv_w, cwt16, relrep, r_index, query,
                                   rp_w1, rp_b1, rp_w2, rp_b2, rel16);
    prep2<<<NE / 256, 256, 0, stream>>>(edge_index, edge_type, edge_weight,
                                        cnt, epack);

    // try the cooperative mega-kernel; fall back to per-layer dispatches
    __half*          a_xa  = x16a;
    __half*          a_xb  = x16b;
    const int*       a_cnt = cnt;
    const int4*      a_ep  = epack;
    const __half*    a_rel = rel16;
    const float*     a_q   = query;
    const int*       a_h   = h_index;
    const _Float16*  a_cw  = cwt16;
    const float*     a_cb  = conv_b;
    const float*     a_g   = ln_g;
    const float*     a_b   = ln_b;
    const int*       a_t   = t_index;
    const float*     a_w1  = mlp_w1;
    const float*     a_b1  = mlp_b1;
    const float*     a_w2  = mlp_w2;
    const float*     a_b2  = mlp_b2;
    float*           a_out = out;
    void* args[17] = {&a_xa, &a_xb, &a_cnt, &a_ep, &a_rel, &a_q, &a_h,
                      &a_cw, &a_cb, &a_g, &a_b, &a_t, &a_w1, &a_b1,
                      &a_w2, &a_b2, &a_out};
    hipError_t cerr = hipLaunchCooperativeKernel((void*)mega, dim3(GRID),
                                                 dim3(256), args, 0, stream);
    if (cerr != hipSuccess) {
        (void)hipGetLastError();   // clear sticky error, take r13 path
        __half* mc = x16a; __half* mn = x16b;
        fused_layer_first_k<<<NN / 4, 256, 0, stream>>>(rel16, cnt, epack,
                                                        query, h_index, cwt16,
                                                        conv_b, ln_g, ln_b, mc);
        for (int l = 1; l < NL; ++l) {
            fused_layer_k<<<NN / 4, 256, 0, stream>>>(mc, rel16 + l * RELSZ,
                                                      cnt, epack, query, h_index,
                                                      cwt16 + l * 8192,
                                                      conv_b + l * ND,
                                                      ln_g + l * ND,
                                                      ln_b + l * ND, mn);
            __half* th = mc; mc = mn; mn = th;
        }
        final_score_k<<<NB * NT / 4, 256, 0, stream>>>(mc, query, t_index,
                                                       mlp_w1, mlp_b1,
                                                       mlp_w2, mlp_b2, out);
    }
}

// Round 16
// 327.372 us; speedup vs baseline: 3.5430x; 3.5430x over previous
//
#include <hip/hip_runtime.h>
#include <hip/hip_fp16.h>

#define NB 4
#define NN 20000
#define NE 320000
#define ND 64
#define NR 64
#define NT 1000
#define NL 6
#define LN_EPS 1e-5f
#define CAP 64   // bucket capacity: deg ~ Poisson(16), P(deg>64) ~ 5e-19

typedef _Float16 half8 __attribute__((ext_vector_type(8)));
typedef _Float16 half4v __attribute__((ext_vector_type(4)));
typedef float floatx4 __attribute__((ext_vector_type(4)));

// r16 = r13 verbatim (proven 324 us). r14/r15 (cooperative mega-kernel) and
// r11 (degree-sort) both regressed; r13 is the measured optimum:
//  - fp16 [N,B,D] node-major state; all math fp32, storage-only rounding
//  - bucketed edge table (node n owns epack[n*64..]): 1-pass atomic build
//  - fused gather(2 edges/wave, 16 B/lane) + MFMA conv + LN + residual
//  - layer-1 specialized for the query-sparse x0 (no x state reads)
//  - 9-dispatch graph; per-layer kernels sit at the random-gather byte floor

// ---------------------------------------------------------------- prep 1
// blocks [0,79): zero cnt ; [79,271): conv_w transpose ; 271: query ;
// [272,656): rel_mlp all layers (wave-local, wave = batch)
__global__ void __launch_bounds__(256)
prep1(int* __restrict__ cnt,
      const float* __restrict__ cw, _Float16* __restrict__ cwt,
      const float* __restrict__ relrep, const int* __restrict__ r_index,
      float* __restrict__ query,
      const float* __restrict__ rp_w1, const float* __restrict__ rp_b1,
      const float* __restrict__ rp_w2, const float* __restrict__ rp_b2,
      __half* __restrict__ rel16) {
    int blk = blockIdx.x, tid = threadIdx.x;
    if (blk < 79) {
        int i = blk * 256 + tid;
        if (i < NN) cnt[i] = 0;
    } else if (blk < 271) {
        int i = (blk - 79) * 256 + tid;             // NL*128*64 = 192*256
        int l = i >> 13, rem = i & 8191, k = rem >> 6, n = rem & 63;
        cwt[l * 8192 + n * 128 + k] = (_Float16)cw[i];
    } else if (blk == 271) {
        int b = tid >> 6, d = tid & 63;
        query[tid] = relrep[(b * NR + r_index[b]) * ND + d];
    } else {
        int u = blk - 272;                          // 0..383 = l*NR + r
        int l = u >> 6, r = u & 63;
        int b = tid >> 6, j = tid & 63;
        const float* w1 = rp_w1 + l * ND * ND;
        const float* w2 = rp_w2 + l * ND * ND;
        float xin = relrep[(b * NR + r) * ND + j];
        float acc = rp_b1[l * ND + j];
        #pragma unroll 8
        for (int k = 0; k < ND; ++k) acc += __shfl(xin, k) * w1[k * ND + j];
        float hmid = fmaxf(acc, 0.f);
        float outv = rp_b2[l * ND + j];
        #pragma unroll 8
        for (int k = 0; k < ND; ++k) outv += __shfl(hmid, k) * w2[k * ND + j];
        rel16[l * (NR * NB * ND) + (r * NB + b) * ND + j] = __float2half(outv);
    }
}

// ---------------------------------------------------------------- prep 2
// one pass: bucket-scatter edges by dst
__global__ void __launch_bounds__(256)
prep2(const int* __restrict__ ei, const int* __restrict__ et,
      const float* __restrict__ ew, int* __restrict__ cnt,
      int4* __restrict__ epack) {
    int e = blockIdx.x * 256 + threadIdx.x;         // NE = 1250*256 exactly
    int d = ei[NE + e];
    int p = atomicAdd(&cnt[d], 1);
    if (p < CAP)
        epack[d * CAP + p] = make_int4(ei[e], et[e], __float_as_int(ew[e]), 0);
}

__device__ __forceinline__ float2 h2f(unsigned u) {
    __half2 h = *(__half2*)&u;
    return __half22float2(h);
}
__device__ __forceinline__ __half2 u2h2(unsigned u) { return *(__half2*)&u; }

// --------------------------------------------- shared epilogue (MFMA+LN)
__device__ __forceinline__ void conv_ln_epilogue(
        _Float16* A16, float* sD, int wv, int lane, int n,
        const _Float16* __restrict__ cwt, const float* __restrict__ cb,
        const float* __restrict__ g, const float* __restrict__ bb,
        __half* __restrict__ xo16) {
    __syncthreads();
    {
        int m = lane & 15, quad = lane >> 4;
        int ncol = wv * 16 + m;
        floatx4 acc = {0.f, 0.f, 0.f, 0.f};
        #pragma unroll
        for (int k0 = 0; k0 < 128; k0 += 32) {
            half8 a = *(const half8*)&A16[m * 136 + k0 + quad * 8];
            half8 bfr = *(const half8*)&cwt[ncol * 128 + k0 + quad * 8];
            acc = __builtin_amdgcn_mfma_f32_16x16x32_f16(a, bfr, acc, 0, 0, 0);
        }
        #pragma unroll
        for (int rg = 0; rg < 4; ++rg)
            sD[(quad * 4 + rg) * 65 + ncol] = acc[rg];
    }
    __syncthreads();
    float gl = g[lane], bl = bb[lane], cbl = cb[lane];
    #pragma unroll
    for (int b = 0; b < NB; ++b) {
        float acc = sD[(wv * 4 + b) * 65 + lane] + cbl;
        float s = acc, s2 = acc * acc;
        #pragma unroll
        for (int o = 32; o > 0; o >>= 1) { s += __shfl_xor(s, o); s2 += __shfl_xor(s2, o); }
        float mu  = s * (1.f / ND);
        float var = s2 * (1.f / ND) - mu * mu;
        float hn  = (acc - mu) * rsqrtf(var + LN_EPS) * gl + bl;
        float xvf = (float)A16[(wv * 4 + b) * 136 + lane];
        float v   = fmaxf(hn, 0.f) + xvf;
        xo16[(n * NB + b) * ND + lane] = __float2half(v);
    }
}

// ------------------------------------------------ layer 1 (x0 query-sparse)
__global__ void __launch_bounds__(256)
fused_layer_first(const __half* __restrict__ rel16,
                  const int* __restrict__ cnt, const int4* __restrict__ epack,
                  const float* __restrict__ query, const int* __restrict__ h_index,
                  const _Float16* __restrict__ cwt, const float* __restrict__ cb,
                  const float* __restrict__ g, const float* __restrict__ bb,
                  __half* __restrict__ xo16) {
    __shared__ _Float16 A16[16 * 136];
    __shared__ float sD[16 * 65];
    int wv = threadIdx.x >> 6;
    int lane = threadIdx.x & 63;
    int n = blockIdx.x * 4 + wv;
    int cn = min(cnt[n], CAP);
    int bidx = lane >> 4, c4 = (lane & 15) << 2;
    int hb = h_index[bidx];

    const uint2* __restrict__ r2 = (const uint2*)rel16;
    float4 q4 = ((const float4*)query)[lane];
    half4v qh;
    qh.x = (_Float16)q4.x; qh.y = (_Float16)q4.y;
    qh.z = (_Float16)q4.z; qh.w = (_Float16)q4.w;
    float qx = (float)qh.x, qy = (float)qh.y, qz = (float)qh.z, qw = (float)qh.w;

    float4 agg4 = make_float4(0.f, 0.f, 0.f, 0.f);
    {
        int4 ed = make_int4(0, 0, 0, 0);
        if (lane < cn) ed = epack[n * CAP + lane];
        for (int j = 0; j < cn; ++j) {
            int s   = __shfl(ed.x, j);
            int t   = __shfl(ed.y, j);
            float w = __int_as_float(__shfl(ed.z, j));
            if (s == hb) {
                uint2 ra = r2[t * 64 + lane];
                float2 q0 = h2f(ra.x), q1 = h2f(ra.y);
                agg4.x = fmaf(qx * q0.x, w, agg4.x);
                agg4.y = fmaf(qy * q0.y, w, agg4.y);
                agg4.z = fmaf(qz * q1.x, w, agg4.z);
                agg4.w = fmaf(qw * q1.y, w, agg4.w);
            }
        }
    }
    if (n == hb) {
        agg4.x += q4.x; agg4.y += q4.y; agg4.z += q4.z; agg4.w += q4.w;
    }
    {
        int r = wv * 4 + bidx;
        half4v xh = {0, 0, 0, 0};
        if (n == hb) xh = qh;
        *(half4v*)&A16[r * 136 + c4] = xh;
        half4v ah;
        ah.x = (_Float16)agg4.x; ah.y = (_Float16)agg4.y;
        ah.z = (_Float16)agg4.z; ah.w = (_Float16)agg4.w;
        *(half4v*)&A16[r * 136 + 64 + c4] = ah;
    }
    conv_ln_epilogue(A16, sD, wv, lane, n, cwt, cb, g, bb, xo16);
}

// ------------------------------------------------ generic fused layer
// two edges per wave; single epack chunk (cnt <= CAP = 64)
__global__ void __launch_bounds__(256)
fused_layer(const __half* __restrict__ x16, const __half* __restrict__ rel16,
            const int* __restrict__ cnt, const int4* __restrict__ epack,
            const float* __restrict__ query, const int* __restrict__ h_index,
            const _Float16* __restrict__ cwt, const float* __restrict__ cb,
            const float* __restrict__ g, const float* __restrict__ bb,
            __half* __restrict__ xo16) {
    __shared__ _Float16 A16[16 * 136];
    __shared__ float sD[16 * 65];
    int wv = threadIdx.x >> 6;
    int lane = threadIdx.x & 63;
    int n = blockIdx.x * 4 + wv;
    int cn = min(cnt[n], CAP);
    int hf = lane >> 5, sub = lane & 31;

    const uint4* __restrict__ x4 = (const uint4*)x16;   // 16 B = 8 halves
    const uint4* __restrict__ r4 = (const uint4*)rel16;

    float acc[8] = {0.f, 0.f, 0.f, 0.f, 0.f, 0.f, 0.f, 0.f};
    {
        int4 ed = make_int4(0, 0, 0, 0);
        if (lane < cn) ed = epack[n * CAP + lane];
        int j = 0;
        for (; j + 4 <= cn; j += 4) {
            int ja = j + hf, jb = j + 2 + hf;
            int sa = __shfl(ed.x, ja), ta = __shfl(ed.y, ja);
            int sb = __shfl(ed.x, jb), tb = __shfl(ed.y, jb);
            float wa = __int_as_float(__shfl(ed.z, ja));
            float wb = __int_as_float(__shfl(ed.z, jb));
            uint4 xa = x4[sa * 32 + sub], ra = r4[ta * 32 + sub];
            uint4 xb = x4[sb * 32 + sub], rb = r4[tb * 32 + sub];
            __half2 p0, p1, p2, p3;
            p0 = __hmul2(u2h2(xa.x), u2h2(ra.x));
            p1 = __hmul2(u2h2(xa.y), u2h2(ra.y));
            p2 = __hmul2(u2h2(xa.z), u2h2(ra.z));
            p3 = __hmul2(u2h2(xa.w), u2h2(ra.w));
            acc[0] = fmaf(__low2float(p0),  wa, acc[0]);
            acc[1] = fmaf(__high2float(p0), wa, acc[1]);
            acc[2] = fmaf(__low2float(p1),  wa, acc[2]);
            acc[3] = fmaf(__high2float(p1), wa, acc[3]);
            acc[4] = fmaf(__low2float(p2),  wa, acc[4]);
            acc[5] = fmaf(__high2float(p2), wa, acc[5]);
            acc[6] = fmaf(__low2float(p3),  wa, acc[6]);
            acc[7] = fmaf(__high2float(p3), wa, acc[7]);
            p0 = __hmul2(u2h2(xb.x), u2h2(rb.x));
            p1 = __hmul2(u2h2(xb.y), u2h2(rb.y));
            p2 = __hmul2(u2h2(xb.z), u2h2(rb.z));
            p3 = __hmul2(u2h2(xb.w), u2h2(rb.w));
            acc[0] = fmaf(__low2float(p0),  wb, acc[0]);
            acc[1] = fmaf(__high2float(p0), wb, acc[1]);
            acc[2] = fmaf(__low2float(p1),  wb, acc[2]);
            acc[3] = fmaf(__high2float(p1), wb, acc[3]);
            acc[4] = fmaf(__low2float(p2),  wb, acc[4]);
            acc[5] = fmaf(__high2float(p2), wb, acc[5]);
            acc[6] = fmaf(__low2float(p3),  wb, acc[6]);
            acc[7] = fmaf(__high2float(p3), wb, acc[7]);
        }
        for (; j < cn; j += 2) {
            int ja = j + hf;                 // zero-padded lanes add exact 0
            int sa = __shfl(ed.x, ja), ta = __shfl(ed.y, ja);
            float wa = __int_as_float(__shfl(ed.z, ja));
            uint4 xa = x4[sa * 32 + sub], ra = r4[ta * 32 + sub];
            __half2 p0 = __hmul2(u2h2(xa.x), u2h2(ra.x));
            __half2 p1 = __hmul2(u2h2(xa.y), u2h2(ra.y));
            __half2 p2 = __hmul2(u2h2(xa.z), u2h2(ra.z));
            __half2 p3 = __hmul2(u2h2(xa.w), u2h2(ra.w));
            acc[0] = fmaf(__low2float(p0),  wa, acc[0]);
            acc[1] = fmaf(__high2float(p0), wa, acc[1]);
            acc[2] = fmaf(__low2float(p1),  wa, acc[2]);
            acc[3] = fmaf(__high2float(p1), wa, acc[3]);
            acc[4] = fmaf(__low2float(p2),  wa, acc[4]);
            acc[5] = fmaf(__high2float(p2), wa, acc[5]);
            acc[6] = fmaf(__low2float(p3),  wa, acc[6]);
            acc[7] = fmaf(__high2float(p3), wa, acc[7]);
        }
    }
    #pragma unroll
    for (int k = 0; k < 8; ++k) acc[k] += __shfl_xor(acc[k], 32);
    int bq = sub >> 3, ch = (sub & 7) << 3;
    if (hf == 0) {
        if (n == h_index[bq]) {
            const float* qp = query + bq * 64 + ch;
            #pragma unroll
            for (int k = 0; k < 8; ++k) acc[k] += qp[k];
        }
        int r = wv * 4 + bq;
        half8 ah;
        #pragma unroll
        for (int k = 0; k < 8; ++k) ah[k] = (_Float16)acc[k];
        *(half8*)&A16[r * 136 + 64 + ch] = ah;
    }
    {
        int bidx = lane >> 4, c4 = (lane & 15) << 2;
        int r = wv * 4 + bidx;
        const uint2* __restrict__ x2 = (const uint2*)x16;
        uint2 xraw = x2[(n * NB + bidx) * 16 + (lane & 15)];
        *(uint2*)&A16[r * 136 + c4] = xraw;
    }
    conv_ln_epilogue(A16, sD, wv, lane, n, cwt, cb, g, bb, xo16);
}

// score[b,t] = relu(concat(x[ti,b,:],query[b,:]) @ W1 + b1) @ W2 + b2
__global__ void final_score(const __half* __restrict__ x16, const float* __restrict__ query,
                            const int* __restrict__ t_index,
                            const float* __restrict__ w1, const float* __restrict__ b1,
                            const float* __restrict__ w2, const float* __restrict__ b2,
                            float* __restrict__ out) {
    int gid = blockIdx.x * 4 + (threadIdx.x >> 6);
    int lane = threadIdx.x & 63;
    int b = gid / NT;
    int ti = t_index[gid];
    float xv = __half2float(x16[(ti * NB + b) * ND + lane]);
    float qv = query[b * ND + lane];
    float a0 = b1[lane], a1 = b1[lane + 64];
    #pragma unroll 8
    for (int k = 0; k < ND; ++k) {
        float f = __shfl(xv, k);
        a0 += f * w1[k * 128 + lane];
        a1 += f * w1[k * 128 + lane + 64];
    }
    #pragma unroll 8
    for (int k = 0; k < ND; ++k) {
        float f = __shfl(qv, k);
        a0 += f * w1[(ND + k) * 128 + lane];
        a1 += f * w1[(ND + k) * 128 + lane + 64];
    }
    a0 = fmaxf(a0, 0.f);
    a1 = fmaxf(a1, 0.f);
    float p = a0 * w2[lane] + a1 * w2[lane + 64];
    #pragma unroll
    for (int o = 32; o > 0; o >>= 1) p += __shfl_xor(p, o);
    if (lane == 0) out[gid] = p + b2[0];
}

extern "C" void kernel_launch(void* const* d_in, const int* in_sizes, int n_in,
                              void* d_out, int out_size, void* d_ws, size_t ws_size,
                              hipStream_t stream) {
    const int*   edge_index  = (const int*)d_in[0];
    const int*   edge_type   = (const int*)d_in[1];
    const float* relrep      = (const float*)d_in[2];
    const int*   h_index     = (const int*)d_in[3];
    const int*   r_index     = (const int*)d_in[4];
    const int*   t_index     = (const int*)d_in[5];
    const float* edge_weight = (const float*)d_in[6];
    const float* rp_w1  = (const float*)d_in[7];
    const float* rp_b1  = (const float*)d_in[8];
    const float* rp_w2  = (const float*)d_in[9];
    const float* rp_b2  = (const float*)d_in[10];
    const float* conv_w = (const float*)d_in[11];
    const float* conv_b = (const float*)d_in[12];
    const float* ln_g   = (const float*)d_in[13];
    const float* ln_b   = (const float*)d_in[14];
    const float* mlp_w1 = (const float*)d_in[15];
    const float* mlp_b1 = (const float*)d_in[16];
    const float* mlp_w2 = (const float*)d_in[17];
    const float* mlp_b2 = (const float*)d_in[18];
    float* out = (float*)d_out;

    const int BND = NB * NN * ND;              // 5,120,000
    const int RELSZ = NR * NB * ND;            // 16384
    float*    ws     = (float*)d_ws;
    float*    query  = ws;                         // 256 f
    __half*   rel16  = (__half*)(query + 256);     // NL*RELSZ halves
    __half*   x16a   = rel16 + NL * RELSZ;         // BND halves
    __half*   x16b   = x16a + BND;                 // BND halves
    _Float16* cwt16  = (_Float16*)(x16b + BND);    // NL*8192 halves
    int4*     epack  = (int4*)(cwt16 + NL * 8192); // NN*CAP int4 (20.5 MB)
    int*      cnt    = (int*)(epack + NN * CAP);   // NN
    // total ≈ 42 MB

    // 9-dispatch graph
    prep1<<<656, 256, 0, stream>>>(cnt, conv_w, cwt16, relrep, r_index, query,
                                   rp_w1, rp_b1, rp_w2, rp_b2, rel16);
    prep2<<<NE / 256, 256, 0, stream>>>(edge_index, edge_type, edge_weight,
                                        cnt, epack);

    __half* mc = x16a; __half* mn = x16b;
    fused_layer_first<<<NN / 4, 256, 0, stream>>>(rel16, cnt, epack,
                                                  query, h_index,
                                                  cwt16, conv_b, ln_g, ln_b, mc);
    for (int l = 1; l < NL; ++l) {
        fused_layer<<<NN / 4, 256, 0, stream>>>(mc, rel16 + l * RELSZ, cnt, epack,
                                                query, h_index,
                                                cwt16 + l * 8192, conv_b + l * ND,
                                                ln_g + l * ND, ln_b + l * ND, mn);
        __half* th = mc; mc = mn; mn = th;
    }
    final_score<<<NB * NT / 4, 256, 0, stream>>>(mc, query, t_index,
                                                 mlp_w1, mlp_b1, mlp_w2, mlp_b2, out);
}